// Round 9
// baseline (181.428 us; speedup 1.0000x reference)
//
#include <hip/hip_runtime.h>

#define NT 64
#define NB 8192
#define NS 32
#define NF 16
#define DT 0.05f
#define FP_ITERS 3

typedef float f32x2 __attribute__((ext_vector_type(2)));
typedef float f32x4 __attribute__((ext_vector_type(4)));

// tanh(x) = 1 - 2/(1 + exp2(K x)), K = 2*log2(e). 6 VALU ops per pair.
__device__ __forceinline__ f32x2 tanh2(f32x2 x) {
    const float K = 2.8853900817779268f;
    float e0 = __builtin_amdgcn_exp2f(K * x[0]);
    float e1 = __builtin_amdgcn_exp2f(K * x[1]);
    float r0 = __builtin_amdgcn_rcpf(e0 + 1.0f);
    float r1 = __builtin_amdgcn_rcpf(e1 + 1.0f);
    f32x2 r;
    r[0] = fmaf(-2.0f, r0, 1.0f);
    r[1] = fmaf(-2.0f, r1, 1.0f);
    return r;
}

// R8 post-mortem: VGPR_Count pinned at 80 across ALL variants while the
// invariant set needs ~96 -> the register allocator is occupancy-chasing
// (~6 waves/EU target ~85 regs) and spilling asm-loaded W/U to scratch
// inside the hot loop (L2-hit scratch: invisible in FETCH_SIZE, visible as
// ~2x VALU-cycle inflation). The grid only supplies 2 waves/SIMD, so that
// occupancy is pure waste. Fix: amdgpu_waves_per_eu(2,2) — min AND max —
// gives the allocator its true budget (512/2 = 256 VGPRs) and removes the
// incentive to spill. Hop bodies additionally pinned to exactly
// 2 DPP + 4 v_fmac_f32 via inline asm (no scalarization slack).
//
// Lane map: lane = b*16 + p; b in [0,4) = batch within wave, p in [0,16) =
// state pair. 4 batches/wave -> 2048 waves = 2/SIMD.
__global__ __launch_bounds__(256)
__attribute__((amdgpu_waves_per_eu(2, 2)))
void rnes_kernel(
    const float* __restrict__ y0,
    const float* __restrict__ forces,
    const float* __restrict__ W,
    const float* __restrict__ U,
    const float* __restrict__ bias,
    float* __restrict__ out)
{
    const int lane = threadIdx.x & 63;
    const int wv   = threadIdx.x >> 6;
    const int b    = lane >> 4;
    const int p    = lane & 15;
    const int batch = blockIdx.x * 16 + wv * 4 + b;

    // One-time DPP direction probe (immune to row_ror receive-direction
    // ambiguity): after ror:1 this lane holds the p of the lane it received
    // from; rotations compose, so ror:j delivers lane (p + dir*j) & 15.
    const int got = __builtin_amdgcn_update_dpp(0, p, 0x121, 0xF, 0xF, true) & 15;
    const int dir = (got == ((p + 1) & 15)) ? 1 : 15;

    // Per-lane addresses of W row 2p, column-pair q, in rotation order.
    const float* aW[16];
#pragma unroll
    for (int j = 0; j < 16; ++j) {
        const int q = (p + dir * j) & 15;
        aW[j] = W + (2*p) * NS + 2*q;
    }

    // WA[j] = (W[2p][2q], W[2p][2q+1]); WB[j] = row 2p+1 via offset:128
    // (row stride 32 floats = 128 B; max addr 990*4+128+8 = 4096 B, in
    // bounds). Inline-asm defs: cannot be rematerialized.
    f32x2 WA[16], WB[16];
#define RNES_LOADW8(D, J0, OFS)                                                \
    asm volatile(                                                              \
        "global_load_dwordx2 %0, %8, off " OFS "\n\t"                          \
        "global_load_dwordx2 %1, %9, off " OFS "\n\t"                          \
        "global_load_dwordx2 %2, %10, off " OFS "\n\t"                         \
        "global_load_dwordx2 %3, %11, off " OFS "\n\t"                         \
        "global_load_dwordx2 %4, %12, off " OFS "\n\t"                         \
        "global_load_dwordx2 %5, %13, off " OFS "\n\t"                         \
        "global_load_dwordx2 %6, %14, off " OFS "\n\t"                         \
        "global_load_dwordx2 %7, %15, off " OFS "\n\t"                         \
        "s_waitcnt vmcnt(0)"                                                   \
        : "=&v"(D[(J0)+0]), "=&v"(D[(J0)+1]), "=&v"(D[(J0)+2]),                \
          "=&v"(D[(J0)+3]), "=&v"(D[(J0)+4]), "=&v"(D[(J0)+5]),                \
          "=&v"(D[(J0)+6]), "=&v"(D[(J0)+7])                                   \
        : "v"(aW[(J0)+0]), "v"(aW[(J0)+1]), "v"(aW[(J0)+2]), "v"(aW[(J0)+3]),  \
          "v"(aW[(J0)+4]), "v"(aW[(J0)+5]), "v"(aW[(J0)+6]), "v"(aW[(J0)+7]))
    RNES_LOADW8(WA, 0, "");
    RNES_LOADW8(WA, 8, "");
    RNES_LOADW8(WB, 0, "offset:128");
    RNES_LOADW8(WB, 8, "offset:128");
#undef RNES_LOADW8

    // U in natural order: UA[f] = (U[2p][2f], U[2p][2f+1]); UB = row 2p+1
    // (+64 B). One base address, immediate offsets 0..120.
    const float* aU = U + (2*p) * NF;
    f32x2 UA[8], UB[8];
    asm volatile(
        "global_load_dwordx2 %0,  %16, off\n\t"
        "global_load_dwordx2 %1,  %16, off offset:8\n\t"
        "global_load_dwordx2 %2,  %16, off offset:16\n\t"
        "global_load_dwordx2 %3,  %16, off offset:24\n\t"
        "global_load_dwordx2 %4,  %16, off offset:32\n\t"
        "global_load_dwordx2 %5,  %16, off offset:40\n\t"
        "global_load_dwordx2 %6,  %16, off offset:48\n\t"
        "global_load_dwordx2 %7,  %16, off offset:56\n\t"
        "global_load_dwordx2 %8,  %16, off offset:64\n\t"
        "global_load_dwordx2 %9,  %16, off offset:72\n\t"
        "global_load_dwordx2 %10, %16, off offset:80\n\t"
        "global_load_dwordx2 %11, %16, off offset:88\n\t"
        "global_load_dwordx2 %12, %16, off offset:96\n\t"
        "global_load_dwordx2 %13, %16, off offset:104\n\t"
        "global_load_dwordx2 %14, %16, off offset:112\n\t"
        "global_load_dwordx2 %15, %16, off offset:120\n\t"
        "s_waitcnt vmcnt(0)"
        : "=&v"(UA[0]), "=&v"(UA[1]), "=&v"(UA[2]), "=&v"(UA[3]),
          "=&v"(UA[4]), "=&v"(UA[5]), "=&v"(UA[6]), "=&v"(UA[7]),
          "=&v"(UB[0]), "=&v"(UB[1]), "=&v"(UB[2]), "=&v"(UB[3]),
          "=&v"(UB[4]), "=&v"(UB[5]), "=&v"(UB[6]), "=&v"(UB[7])
        : "v"(aU));

    const f32x2 b2 = *(const f32x2*)(bias + 2*p);

    // y_prev, out[0] = y0
    f32x2 yp = *(const f32x2*)(y0 + (size_t)batch * NS + 2*p);
    __builtin_nontemporal_store(yp, (f32x2*)(out + (size_t)batch * NS + 2*p));

    // register prefetch of forces[1]: broadcast f32x4 x4 per b-group.
    const size_t fstep = (size_t)NB * NF;
    const f32x4* fb = (const f32x4*)(forces + (size_t)batch * NF);
    f32x4 upf[4];
#pragma unroll
    for (int j = 0; j < 4; ++j)
        upf[j] = __builtin_nontemporal_load(&fb[(fstep >> 2) + j]);

    for (int k = 1; k < NT; ++k) {
        // fu = U u + b, packed: sA accumulates both halves of row 2p.
        f32x2 sA = (f32x2){0.f, 0.f}, sB = (f32x2){0.f, 0.f};
#pragma unroll
        for (int f = 0; f < 8; ++f) {
            f32x4 u4 = upf[f >> 1];
            f32x2 u2 = (f & 1) ? (f32x2){u4[2], u4[3]} : (f32x2){u4[0], u4[1]};
            sA = UA[f] * u2 + sA;
            sB = UB[f] * u2 + sB;
        }
        const float fu0 = b2[0] + sA[0] + sA[1];
        const float fu1 = b2[1] + sB[0] + sB[1];

        // prefetch next step's forces (in flight across all 3 iterations)
        {
            int kn = (k + 1 < NT) ? (k + 1) : (NT - 1);
#pragma unroll
            for (int j = 0; j < 4; ++j)
                upf[j] = __builtin_nontemporal_load(&fb[(size_t)kn * (fstep >> 2) + j]);
        }

        // fixed-point iterations, warm start y_prev. Pure-register: 15
        // INDEPENDENT row_ror:j hops (builtin DPP — compiler inserts the
        // required hazard nops) + exactly 4 v_fmac_f32 per hop via asm
        // (accumulation order identical to R6: r00+r01 / r10+r11 at end).
        f32x2 y = yp;
#pragma unroll
        for (int it = 0; it < FP_ITERS; ++it) {
            const int y0i = __float_as_int(y[0]);
            const int y1i = __float_as_int(y[1]);
            float r00 = fu0, r01 = 0.f, r10 = fu1, r11 = 0.f;
            // j = 0: own pair, no hop
            asm volatile(
                "v_fmac_f32 %0, %4, %8\n\t"
                "v_fmac_f32 %1, %5, %9\n\t"
                "v_fmac_f32 %2, %6, %8\n\t"
                "v_fmac_f32 %3, %7, %9"
                : "+v"(r00), "+v"(r01), "+v"(r10), "+v"(r11)
                : "v"(WA[0][0]), "v"(WA[0][1]), "v"(WB[0][0]), "v"(WB[0][1]),
                  "v"(y[0]), "v"(y[1]));
#define RNES_HOP(J)                                                            \
            {                                                                  \
                float y0q = __int_as_float(__builtin_amdgcn_update_dpp(        \
                    0, y0i, 0x120 + (J), 0xF, 0xF, true));                     \
                float y1q = __int_as_float(__builtin_amdgcn_update_dpp(        \
                    0, y1i, 0x120 + (J), 0xF, 0xF, true));                     \
                asm volatile(                                                  \
                    "v_fmac_f32 %0, %4, %8\n\t"                                \
                    "v_fmac_f32 %1, %5, %9\n\t"                                \
                    "v_fmac_f32 %2, %6, %8\n\t"                                \
                    "v_fmac_f32 %3, %7, %9"                                    \
                    : "+v"(r00), "+v"(r01), "+v"(r10), "+v"(r11)               \
                    : "v"(WA[J][0]), "v"(WA[J][1]),                            \
                      "v"(WB[J][0]), "v"(WB[J][1]),                            \
                      "v"(y0q), "v"(y1q));                                     \
            }
            RNES_HOP(1)  RNES_HOP(2)  RNES_HOP(3)  RNES_HOP(4)
            RNES_HOP(5)  RNES_HOP(6)  RNES_HOP(7)  RNES_HOP(8)
            RNES_HOP(9)  RNES_HOP(10) RNES_HOP(11) RNES_HOP(12)
            RNES_HOP(13) RNES_HOP(14) RNES_HOP(15)
#undef RNES_HOP
            f32x2 zt;
            zt[0] = r00 + r01;
            zt[1] = r10 + r11;
            f32x2 t = tanh2(zt);
            y[0] = fmaf(DT, t[0], yp[0]);
            y[1] = fmaf(DT, t[1], yp[1]);
        }

        yp = y;
        __builtin_nontemporal_store(y, (f32x2*)(out + ((size_t)k * NB + batch) * NS + 2*p));
    }
}

extern "C" void kernel_launch(void* const* d_in, const int* in_sizes, int n_in,
                              void* d_out, int out_size, void* d_ws, size_t ws_size,
                              hipStream_t stream) {
    const float* y0     = (const float*)d_in[0];
    const float* forces = (const float*)d_in[1];
    const float* W      = (const float*)d_in[2];
    const float* U      = (const float*)d_in[3];
    const float* b      = (const float*)d_in[4];
    float* out = (float*)d_out;

    dim3 grid(NB / 16);   // 512 blocks x 4 waves x 4 batches = 8192
    dim3 block(256);
    rnes_kernel<<<grid, block, 0, stream>>>(y0, forces, W, U, b, out);
}

// Round 10
// 160.096 us; speedup vs baseline: 1.1332x; 1.1332x over previous
//
#include <hip/hip_runtime.h>

#define NT 64
#define NB 8192
#define NS 32
#define NF 16
#define DT 0.05f

typedef float f32x2 __attribute__((ext_vector_type(2)));
typedef float f32x4 __attribute__((ext_vector_type(4)));

// tanh(x) = 1 - 2/(1 + exp2(K x)), K = 2*log2(e). 6 VALU ops per pair.
__device__ __forceinline__ f32x2 tanh2(f32x2 x) {
    const float K = 2.8853900817779268f;
    float e0 = __builtin_amdgcn_exp2f(K * x[0]);
    float e1 = __builtin_amdgcn_exp2f(K * x[1]);
    float r0 = __builtin_amdgcn_rcpf(e0 + 1.0f);
    float r1 = __builtin_amdgcn_rcpf(e1 + 1.0f);
    f32x2 r;
    r[0] = fmaf(-2.0f, r0, 1.0f);
    r[1] = fmaf(-2.0f, r1, 1.0f);
    return r;
}

// Base = R6 structure (measured best: 82.6us dispatch), DPP ring exchange +
// packed pk_fma, no LDS, no barriers. R7-R9 (forced residency via asm loads,
// waves_per_eu(2,2), asm fmac) all failed to move VGPR/time -> allocator
// fight abandoned.
//
// NEW (R10): predictor-corrector. 3 warm-start fixed-point iters are replaced
// by LINEAR EXTRAPOLATION (y_guess = 2*y_{k-1} - y_{k-2}) + 2 iterations.
// Error model: contraction L = DT*||W|| ~= 0.1; warm start err ~DT=5e-2 ->
// 3 iters = 5e-5/step. Extrapolated guess err ~DT^2*y'' ~= 2.5e-3 -> 2 iters
// = 2.5e-5/step (BETTER than current). k=1 has no history: ypp=yp makes the
// extrapolation collapse to warm start, and a uniform-branch 3rd iteration
// keeps its accuracy. Saves ~27% of per-step work on 62/63 steps.
//
// Lane map: lane = b*16 + p; b in [0,4) = batch within wave, p in [0,16) =
// state pair. 4 batches/wave -> 2048 waves = 2/SIMD.
__global__ __launch_bounds__(256, 2) void rnes_kernel(
    const float* __restrict__ y0,
    const float* __restrict__ forces,
    const float* __restrict__ W,
    const float* __restrict__ U,
    const float* __restrict__ bias,
    float* __restrict__ out)
{
    const int lane = threadIdx.x & 63;
    const int wv   = threadIdx.x >> 6;
    const int b    = lane >> 4;
    const int p    = lane & 15;
    const int batch = blockIdx.x * 16 + wv * 4 + b;

    // One-time DPP direction probe (immune to row_ror receive-direction
    // ambiguity): after ror:1 this lane holds the p of the lane it received
    // from; rotations compose, so ror:j delivers lane (p + dir*j) & 15.
    const int got = __builtin_amdgcn_update_dpp(0, p, 0x121, 0xF, 0xF, true) & 15;
    const int dir = (got == ((p + 1) & 15)) ? 1 : 15;

    // W gathered in rotation order as contiguous column pairs:
    // WA[j] = (W[2p][2q], W[2p][2q+1]), WB[j] = same for row 2p+1. 64 VGPRs.
    f32x2 WA[16], WB[16];
#pragma unroll
    for (int j = 0; j < 16; ++j) {
        const int q = (p + dir * j) & 15;
        WA[j] = *(const f32x2*)(W + (2*p)   * NS + 2*q);
        WB[j] = *(const f32x2*)(W + (2*p+1) * NS + 2*q);
    }
#pragma unroll
    for (int j = 0; j < 16; ++j)
        asm volatile("" : "+v"(WA[j]), "+v"(WB[j]));   // anti-remat pin

    // U as packed feature pairs: UA[f] = (U[2p][2f], U[2p][2f+1]). 32 VGPRs.
    f32x2 UA[8], UB[8];
#pragma unroll
    for (int f = 0; f < 8; ++f) {
        UA[f] = *(const f32x2*)(U + (2*p)   * NF + 2*f);
        UB[f] = *(const f32x2*)(U + (2*p+1) * NF + 2*f);
    }
#pragma unroll
    for (int f = 0; f < 8; ++f)
        asm volatile("" : "+v"(UA[f]), "+v"(UB[f]));   // anti-remat pin

    const f32x2 b2 = *(const f32x2*)(bias + 2*p);

    // y_prev, out[0] = y0
    f32x2 yp = *(const f32x2*)(y0 + (size_t)batch * NS + 2*p);
    __builtin_nontemporal_store(yp, (f32x2*)(out + (size_t)batch * NS + 2*p));
    f32x2 ypp = yp;   // predictor history; k=1 extrapolation collapses to yp

    // register prefetch of forces[1]: broadcast f32x4 x4 per b-group.
    const size_t fstep = (size_t)NB * NF;
    const f32x4* fb = (const f32x4*)(forces + (size_t)batch * NF);
    f32x4 upf[4];
#pragma unroll
    for (int j = 0; j < 4; ++j)
        upf[j] = __builtin_nontemporal_load(&fb[(fstep >> 2) + j]);

    for (int k = 1; k < NT; ++k) {
        // fu = U u + b, packed: sA accumulates both halves of row 2p.
        f32x2 sA = (f32x2){0.f, 0.f}, sB = (f32x2){0.f, 0.f};
#pragma unroll
        for (int f = 0; f < 8; ++f) {
            f32x4 u4 = upf[f >> 1];
            f32x2 u2 = (f & 1) ? (f32x2){u4[2], u4[3]} : (f32x2){u4[0], u4[1]};
            sA = UA[f] * u2 + sA;
            sB = UB[f] * u2 + sB;
        }
        const float fu0 = b2[0] + sA[0] + sA[1];
        const float fu1 = b2[1] + sB[0] + sB[1];

        // prefetch next step's forces (in flight across the iterations)
        {
            int kn = (k + 1 < NT) ? (k + 1) : (NT - 1);
#pragma unroll
            for (int j = 0; j < 4; ++j)
                upf[j] = __builtin_nontemporal_load(&fb[(size_t)kn * (fstep >> 2) + j]);
        }

        // predictor: linear extrapolation from the two previous time steps.
        f32x2 y;
        y[0] = yp[0] + (yp[0] - ypp[0]);
        y[1] = yp[1] + (yp[1] - ypp[1]);

        // corrector: fixed-point iteration y <- yp + DT*tanh(W y + fu).
        // Pure-register: 15 INDEPENDENT row_ror:j hops, packed FMA.
        auto iterate = [&]() {
            const int y0i = __float_as_int(y[0]);
            const int y1i = __float_as_int(y[1]);
            f32x2 accA = (f32x2){fu0, 0.f};
            f32x2 accB = (f32x2){fu1, 0.f};
            // j = 0: own pair, no hop
            accA = WA[0] * y + accA;
            accB = WB[0] * y + accB;
#define RNES_HOP(J)                                                            \
            {                                                                  \
                f32x2 yq;                                                      \
                yq[0] = __int_as_float(__builtin_amdgcn_update_dpp(            \
                    0, y0i, 0x120 + (J), 0xF, 0xF, true));                     \
                yq[1] = __int_as_float(__builtin_amdgcn_update_dpp(            \
                    0, y1i, 0x120 + (J), 0xF, 0xF, true));                     \
                accA = WA[J] * yq + accA;                                      \
                accB = WB[J] * yq + accB;                                      \
            }
            RNES_HOP(1)  RNES_HOP(2)  RNES_HOP(3)  RNES_HOP(4)
            RNES_HOP(5)  RNES_HOP(6)  RNES_HOP(7)  RNES_HOP(8)
            RNES_HOP(9)  RNES_HOP(10) RNES_HOP(11) RNES_HOP(12)
            RNES_HOP(13) RNES_HOP(14) RNES_HOP(15)
#undef RNES_HOP
            f32x2 zt;
            zt[0] = accA[0] + accA[1];
            zt[1] = accB[0] + accB[1];
            f32x2 t = tanh2(zt);
            y[0] = fmaf(DT, t[0], yp[0]);
            y[1] = fmaf(DT, t[1], yp[1]);
        };
        iterate();
        iterate();
        if (k == 1) iterate();   // no extrapolation history at k=1: keep 3rd
                                 // iter (wave-uniform branch, one step only)

        ypp = yp;
        yp = y;
        __builtin_nontemporal_store(y, (f32x2*)(out + ((size_t)k * NB + batch) * NS + 2*p));
    }
}

extern "C" void kernel_launch(void* const* d_in, const int* in_sizes, int n_in,
                              void* d_out, int out_size, void* d_ws, size_t ws_size,
                              hipStream_t stream) {
    const float* y0     = (const float*)d_in[0];
    const float* forces = (const float*)d_in[1];
    const float* W      = (const float*)d_in[2];
    const float* U      = (const float*)d_in[3];
    const float* b      = (const float*)d_in[4];
    float* out = (float*)d_out;

    dim3 grid(NB / 16);   // 512 blocks x 4 waves x 4 batches = 8192
    dim3 block(256);
    rnes_kernel<<<grid, block, 0, stream>>>(y0, forces, W, U, b, out);
}